// Round 1
// 127.404 us; speedup vs baseline: 1.0681x; 1.0681x over previous
//
#include <hip/hip_runtime.h>
#include <hip/hip_bf16.h>
#include <cstdint>

typedef __attribute__((ext_vector_type(8))) short bf16x8;
typedef __attribute__((ext_vector_type(4))) float f32x4;

static __device__ __forceinline__ float lo16(uint32_t u){ return __uint_as_float(u << 16); }
static __device__ __forceinline__ float hi16(uint32_t u){ return __uint_as_float(u & 0xffff0000u); }
static __device__ __forceinline__ uint32_t f2bf(float x){
    uint32_t u = __float_as_uint(x);
    return (u + 0x7fffu + ((u >> 16) & 1u)) >> 16;
}
static __device__ __forceinline__ uint32_t pack2(float a, float b){
    return f2bf(a) | (f2bf(b) << 16);
}

// ---------------- K1: kf packed bf16 (pure projection) ----------------
// grid 256 = (b, 128 i-groups of 4); block 1024 (16 waves -> 4 waves/SIMD)
// Each output (i,d) computed by 8 threads (32 c each), combined via LDS reduce.
__global__ __launch_bounds__(1024) void k_kf(const float* __restrict__ k,
    const float* __restrict__ Wk, const float* __restrict__ bk,
    uint32_t* __restrict__ kf_pack)
{
    __shared__ float Wk_s[8192];
    __shared__ float bk_s[32];
    __shared__ float red[32][32];
    int t = threadIdx.x;
    for (int L = t; L < 8192; L += 1024) Wk_s[L] = Wk[L];
    if (t < 32) bk_s[t] = bk[t];
    __syncthreads();
    int blk = blockIdx.x;
    int b = blk >> 7, i0 = (blk & 127) * 4;
    int d = t & 31, sub = t >> 5;          // sub 0..31
    int i = i0 + (sub >> 3);               // 4 i per block
    int cp = sub & 7;                      // 8-way c split (32 c each)
    const float* kb = k + (size_t)b * 131072;
    float acc = 0.f;
    #pragma unroll 8
    for (int cc = 0; cc < 32; ++cc){
        int c = cp*32 + cc;
        acc += kb[c*512 + i] * Wk_s[c*32 + d];
    }
    red[sub][d] = acc;
    __syncthreads();
    if (t < 128){
        int isel = t >> 5, dd = t & 31;
        float s = bk_s[dd];
        #pragma unroll
        for (int cp2 = 0; cp2 < 8; ++cp2) s += red[isel*8 + cp2][dd];
        float sO = __shfl_xor(s, 1, 64);
        if ((dd & 1) == 0)
            kf_pack[(b*512 + i0 + isel)*16 + (dd >> 1)] = pack2(s, sO);
    }
}

// ---------------- K2: qb packed bf16 (pure projection) ----------------
// grid 256 = (bg, j-half); block 1024 (16 waves -> 4 waves/SIMD)
__global__ __launch_bounds__(1024) void k_qb(const float* __restrict__ q,
    const float* __restrict__ Wq, const float* __restrict__ bq,
    uint32_t* __restrict__ qb_pack)
{
    __shared__ float Wq_s[1024], bq_s[32], q_s[8192];   // q_s: 32 c x 256 j
    int t = threadIdx.x;
    int blk = blockIdx.x;
    int bg = blk >> 1, h = blk & 1;
    int b = bg >> 6, g = bg & 63;
    int bh = g >> 4, bw = (g >> 2) & 3, bd = g & 3;
    Wq_s[t & 1023] = Wq[t & 1023];
    if (t < 32) bq_s[t] = bq[t];
    const float* qbase = q + (size_t)b * 1048576;
    #pragma unroll
    for (int m = 0; m < 2; ++m){
        int L4 = m*1024 + t;
        int f4 = L4 & 1, iw = (L4 >> 1) & 7, ihl = (L4 >> 4) & 3, c = L4 >> 6;
        const float* src = qbase + c*32768 + (bh*8 + h*4 + ihl)*1024
                         + (bw*8 + iw)*32 + bd*8 + f4*4;
        float4 v = *(const float4*)src;
        *(float4*)&q_s[c*256 + ihl*64 + iw*8 + f4*4] = v;
    }
    __syncthreads();
    int d = t & 31, sub = t >> 5;          // sub 0..31
    uint32_t* qb_out = qb_pack + (size_t)bg * 8192 + h*4096;
    for (int it = 0; it < 8; ++it){
        int jl = it*32 + sub;
        float acc = bq_s[d];
        #pragma unroll
        for (int c = 0; c < 32; ++c)
            acc += q_s[c*256 + jl] * Wq_s[c*32 + d];
        float accO = __shfl_xor(acc, 1, 64);
        if ((d & 1) == 0) qb_out[jl*16 + (d >> 1)] = pack2(acc, accO);
    }
}

// ---------------- K3: self-contained MFMA attention ----------------
// grid 256 = (bg, j-half); block 1024 = 16 waves (4/SIMD); ~110 KB LDS -> 1 block/CU.
// Each wave owns exactly one 16-j tile of the 256-j half.
__global__ __launch_bounds__(1024) void k_attn_mfma(const uint32_t* __restrict__ kf_pack,
    const uint32_t* __restrict__ qb_pack,
    float* __restrict__ oraw, float* __restrict__ mnp, float* __restrict__ mxp)
{
    __shared__ uint32_t kfs32[8192];     // 32 KB: full kf [512 i][16 dp] swizzled
    __shared__ uint16_t qbV16[16384];    // 32 KB: qb^T [32 d][512 i] swizzled
    __shared__ uint16_t Ps16[16384];     // 32 KB: per-wave P [16 j][64 i]
    __shared__ float mred[16][64];       // 4 KB: per wave {mnA[16],mnB[16],mxA[16],mxB[16]}
    __shared__ float stat[64][32];       // 8 KB: prologue reduce scratch
    __shared__ float dens[16][16];
    __shared__ float knsh[32], vssh[32], dsh[32];
    __shared__ float denom_s;
    int t = threadIdx.x;
    int blk = blockIdx.x;
    int bg = blk >> 1, jhalf = blk & 1;
    int b = bg >> 6;
    // ---- stage kf (full 512 i) ----
    {
        const uint32_t* src = kf_pack + b*8192;
        #pragma unroll
        for (int m = 0; m < 8; ++m){
            int flat = m*1024 + t;
            uint32_t v = src[flat];
            int i = flat >> 4, dp = flat & 15;
            kfs32[i*16 + (((dp>>2) ^ (i&3)) & 3)*4 + (dp&3)] = v;
        }
    }
    // ---- stage qbV (full 512 i) ----
    {
        const uint32_t* src = qb_pack + (size_t)bg*8192;
        #pragma unroll
        for (int m = 0; m < 8; ++m){
            int flat = m*1024 + t;
            int i = flat >> 4, dp = flat & 15;
            uint32_t v = src[flat];
            int d0 = 2*dp, d1 = 2*dp + 1;
            qbV16[d0*512 + (((i>>3) ^ (d0&7)) & 63)*8 + (i&7)] = (uint16_t)(v & 0xffffu);
            qbV16[d1*512 + (((i>>3) ^ (d1&7)) & 63)*8 + (i&7)] = (uint16_t)(v >> 16);
        }
    }
    __syncthreads();
    // ---- prologue 1: knorm2 from staged kf ----
    {
        int dp = t & 15, ig = t >> 4;            // 64 groups of 8 i
        float lo2 = 0.f, hi2 = 0.f;
        #pragma unroll
        for (int ii = 0; ii < 8; ++ii){
            int i = ig*8 + ii;
            uint32_t u = kfs32[i*16 + (((dp>>2) ^ (i&3)) & 3)*4 + (dp&3)];
            float a = lo16(u), c = hi16(u);
            lo2 += a*a; hi2 += c*c;
        }
        stat[ig][dp*2] = lo2; stat[ig][dp*2+1] = hi2;
    }
    __syncthreads();
    if (t < 32){
        float s = 0.f;
        #pragma unroll
        for (int u = 0; u < 64; ++u) s += stat[u][t];
        knsh[t] = s;
    }
    __syncthreads();
    // ---- prologue 2: qn2 + vsum from staged qb ----
    {
        int d = t & 31, ig = t >> 5;             // 32 groups of 16 i
        float q2 = 0.f, vs = 0.f;
        #pragma unroll
        for (int ii = 0; ii < 16; ii += 2){
            int i = ig*16 + ii;
            uint32_t u = *(__shared__ uint32_t*)&qbV16[d*512 + (((i>>3) ^ (d&7)) & 63)*8 + (i&7)];
            float a = lo16(u), c = hi16(u);
            q2 += a*a + c*c; vs += a + c;
        }
        stat[ig][d] = q2; stat[32 + ig][d] = vs;
    }
    __syncthreads();
    if (t < 32){
        float q2 = 0.f, vs = 0.f;
        #pragma unroll
        for (int u = 0; u < 32; ++u){ q2 += stat[u][t]; vs += stat[32+u][t]; }
        vssh[t] = vs;
        dsh[t] = sqrtf(knsh[t]) * sqrtf(q2);
    }
    __syncthreads();
    if (t == 0){
        float s = 0.f;
        #pragma unroll
        for (int d2 = 0; d2 < 32; ++d2) s += dsh[d2];
        denom_s = s + 1e-4f;
    }
    __syncthreads();
    float rden = 1.0f / denom_s;
    int wave = t >> 6, lane = t & 63;
    int ln15 = lane & 15, quad = lane >> 4;
    uint16_t* Pw = Ps16 + wave*1024;
    float vs0[4], vs1[4];
    #pragma unroll
    for (int r = 0; r < 4; ++r){
        vs0[r] = vssh[quad*4 + r];
        vs1[r] = vssh[16 + quad*4 + r];
    }
    float* obase = oraw + (size_t)bg * 16384;
    // ---- main: 1 j-tile per wave ----
    int jloc = wave*16 + ln15;                   // within half
    int jglob = jhalf*256 + jloc;
    union { bf16x8 v; uint16_t u[8]; } afr;
    #pragma unroll
    for (int jj = 0; jj < 8; ++jj){
        int d = quad*8 + jj;
        afr.u[jj] = qbV16[d*512 + (((jglob>>3) ^ (d&7)) & 63)*8 + (jglob&7)];
    }
    f32x4 pv0 = {0.f,0.f,0.f,0.f}, pv1 = {0.f,0.f,0.f,0.f};
    float pdn[4] = {0.f,0.f,0.f,0.f};
    for (int sb = 0; sb < 4; ++sb){              // 128 i each
        f32x4 sacc[8];
        #pragma unroll
        for (int u = 0; u < 8; ++u){
            int i = sb*128 + u*16 + ln15;
            bf16x8 bfr = *(__shared__ bf16x8*)&kfs32[i*16 + ((quad ^ (i&3)) & 3)*4];
            f32x4 z = {0.f,0.f,0.f,0.f};
            sacc[u] = __builtin_amdgcn_mfma_f32_16x16x32_bf16(afr.v, bfr, z, 0, 0, 0);
        }
        #pragma unroll
        for (int h2 = 0; h2 < 2; ++h2){
            #pragma unroll
            for (int u4 = 0; u4 < 4; ++u4){
                int u = h2*4 + u4;
                int il = u4*16 + ln15;
                #pragma unroll
                for (int r = 0; r < 4; ++r){
                    float x = sacc[u][r] * rden;
                    float e = x + x*x*(0.5f + x*(1.0f/6.0f));
                    pdn[r] += e;
                    int jrow = quad*4 + r;
                    Pw[jrow*64 + (((il>>3) ^ (jrow&3)) & 7)*8 + (il&7)] = (uint16_t)f2bf(e);
                }
            }
            __threadfence_block();
            #pragma unroll
            for (int ks = 0; ks < 2; ++ks){
                int i0 = ks*32 + quad*8;
                bf16x8 bp = *(__shared__ bf16x8*)&Pw[ln15*64 + (((i0>>3) ^ (ln15&3)) & 7)*8];
                int ig = sb*128 + h2*64 + i0;
                int c0 = ln15, c1 = 16 + ln15;
                bf16x8 av0 = *(__shared__ bf16x8*)&qbV16[c0*512 + (((ig>>3) ^ (c0&7)) & 63)*8];
                bf16x8 av1 = *(__shared__ bf16x8*)&qbV16[c1*512 + (((ig>>3) ^ (c1&7)) & 63)*8];
                pv0 = __builtin_amdgcn_mfma_f32_16x16x32_bf16(av0, bp, pv0, 0, 0, 0);
                pv1 = __builtin_amdgcn_mfma_f32_16x16x32_bf16(av1, bp, pv1, 0, 0, 0);
            }
        }
    }
    // ---- epilogue: denom, o write, per-tile min/max ----
    #pragma unroll
    for (int r = 0; r < 4; ++r){
        float s = pdn[r];
        s += __shfl_xor(s, 1, 64);
        s += __shfl_xor(s, 2, 64);
        s += __shfl_xor(s, 4, 64);
        s += __shfl_xor(s, 8, 64);
        if (ln15 == 0) dens[wave][quad*4 + r] = s;
    }
    __threadfence_block();
    float rl = 1.0f / (512.f + dens[wave][ln15]);
    float o0[4], o1[4];
    #pragma unroll
    for (int r = 0; r < 4; ++r){
        o0[r] = (vs0[r] + pv0[r]) * rl;
        o1[r] = (vs1[r] + pv1[r]) * rl;
        obase[(quad*4 + r)*512 + jglob]      = o0[r];
        obase[(16 + quad*4 + r)*512 + jglob] = o1[r];
    }
    #pragma unroll
    for (int r = 0; r < 4; ++r){
        float mnA = o0[r], mxA = o0[r], mnB = o1[r], mxB = o1[r];
        #pragma unroll
        for (int off = 1; off < 16; off <<= 1){
            mnA = fminf(mnA, __shfl_xor(mnA, off, 64));
            mxA = fmaxf(mxA, __shfl_xor(mxA, off, 64));
            mnB = fminf(mnB, __shfl_xor(mnB, off, 64));
            mxB = fmaxf(mxB, __shfl_xor(mxB, off, 64));
        }
        if (ln15 == 0){
            mred[wave][quad*4 + r]      = mnA;
            mred[wave][32 + quad*4 + r] = mxA;
            mred[wave][16 + quad*4 + r] = mnB;
            mred[wave][48 + quad*4 + r] = mxB;
        }
    }
    __syncthreads();
    if (t < 32){
        float mn = 3e38f, mx = -3e38f;
        #pragma unroll
        for (int w = 0; w < 16; ++w){
            mn = fminf(mn, mred[w][t]);
            mx = fmaxf(mx, mred[w][32 + t]);
        }
        int slot = (bg*2 + jhalf)*32 + t;
        mnp[slot] = mn;
        mxp[slot] = mx;
    }
}

// ---------------- K4: scrambled gather + fused renorm + Wp projection ----------------
// grid 2048; block 256; 32 positions/block, 4 gathers+outputs per thread
__global__ __launch_bounds__(256) void k_proj(const float* __restrict__ oraw,
    const float* __restrict__ mnp, const float* __restrict__ mxp,
    const float* __restrict__ Wp, const float* __restrict__ bp,
    float* __restrict__ out)
{
    __shared__ float Wp_s[1024], bp_s[32];
    __shared__ float sh_v[32][32];
    __shared__ float sh_o[32][33];
    int t = threadIdx.x;
    if (t < 32) bp_s[t] = bp[t];
    for (int L = t; L < 1024; L += 256) Wp_s[L] = Wp[L];
    int blk = blockIdx.x;
    int b = blk >> 10, p0 = (blk & 1023) * 32;
    int c = t & 31, ip0 = t >> 5;
    float vv[4];
    #pragma unroll
    for (int m = 0; m < 4; ++m){
        int p = p0 + m*8 + ip0;
        int h = p >> 10, w = (p >> 5) & 31, dsp = p & 31;
        int f = (h >> 3)*262144 + (w >> 3)*65536 + (dsp >> 3)*16384
              + (h & 7)*2048 + (w & 7)*256 + (dsp & 7)*32;
        int flat = f + c;
        int cidx = b*2048 + (flat >> 9);         // bg*32 + channel
        int s0 = ((cidx >> 5) << 6) + (cidx & 31);
        float o  = oraw[(size_t)b*1048576 + flat];
        float mn = fminf(mnp[s0], mnp[s0 + 32]);
        float mx = fmaxf(mxp[s0], mxp[s0 + 32]);
        vv[m] = (o - mn) / (mx - mn + 1e-4f);
    }
    __syncthreads();
    #pragma unroll
    for (int m = 0; m < 4; ++m) sh_v[m*8 + ip0][c] = vv[m];
    __syncthreads();
    #pragma unroll
    for (int m = 0; m < 4; ++m){
        int pos = m*8 + ip0;
        float acc = bp_s[c];
        #pragma unroll
        for (int cc = 0; cc < 32; ++cc)
            acc += sh_v[pos][cc] * Wp_s[cc*32 + c];
        sh_o[pos][c] = acc;
    }
    __syncthreads();
    #pragma unroll
    for (int m = 0; m < 4; ++m){
        int e = m*8 + (t >> 5), pi = t & 31;
        out[((size_t)(b*32 + e) << 15) + p0 + pi] = sh_o[pi][e];
    }
}

extern "C" void kernel_launch(void* const* d_in, const int* in_sizes, int n_in,
                              void* d_out, int out_size, void* d_ws, size_t ws_size,
                              hipStream_t stream)
{
    const float* q  = (const float*)d_in[0];
    const float* k  = (const float*)d_in[1];
    const float* Wq = (const float*)d_in[2];
    const float* bq = (const float*)d_in[3];
    const float* Wk = (const float*)d_in[4];
    const float* bk = (const float*)d_in[5];
    const float* Wp = (const float*)d_in[6];
    const float* bp = (const float*)d_in[7];

    float* base      = (float*)d_ws;
    uint32_t* kf_pack = (uint32_t*)base;                // 16384 u32
    uint32_t* qb_pack = (uint32_t*)(base + 16384);      // 1,048,576 u32
    float* oraw      = base + 1064960;                  // 2,097,152 f
    float* mnp       = base + 3162112;                  // 8192 f
    float* mxp       = base + 3170304;                  // 8192 f (~12.7 MB total)
    float* outp      = (float*)d_out;

    hipLaunchKernelGGL(k_kf,        dim3(256),  dim3(1024), 0, stream, k, Wk, bk, kf_pack);
    hipLaunchKernelGGL(k_qb,        dim3(256),  dim3(1024), 0, stream, q, Wq, bq, qb_pack);
    hipLaunchKernelGGL(k_attn_mfma, dim3(256),  dim3(1024), 0, stream, kf_pack, qb_pack, oraw, mnp, mxp);
    hipLaunchKernelGGL(k_proj,      dim3(2048), dim3(256), 0, stream, oraw, mnp, mxp, Wp, bp, outp);
}

// Round 2
// 110.202 us; speedup vs baseline: 1.2349x; 1.1561x over previous
//
#include <hip/hip_runtime.h>
#include <hip/hip_bf16.h>
#include <cstdint>

typedef __attribute__((ext_vector_type(8))) short bf16x8;
typedef __attribute__((ext_vector_type(4))) float f32x4;

static __device__ __forceinline__ float lo16(uint32_t u){ return __uint_as_float(u << 16); }
static __device__ __forceinline__ float hi16(uint32_t u){ return __uint_as_float(u & 0xffff0000u); }
static __device__ __forceinline__ uint32_t f2bf(float x){
    uint32_t u = __float_as_uint(x);
    return (u + 0x7fffu + ((u >> 16) & 1u)) >> 16;
}
static __device__ __forceinline__ uint32_t pack2(float a, float b){
    return f2bf(a) | (f2bf(b) << 16);
}
static __device__ __forceinline__ uint32_t cvtpk(float a, float b){
    uint32_t r;
    asm("v_cvt_pk_bf16_f32 %0, %1, %2" : "=v"(r) : "v"(a), "v"(b));
    return r;
}
static __device__ __forceinline__ void pl32swap(uint32_t &x, uint32_t &y){
    asm("v_permlane32_swap_b32 %0, %1" : "+v"(x), "+v"(y));
}
static __device__ __forceinline__ void pl16swap(uint32_t &x, uint32_t &y){
    asm("v_permlane16_swap_b32 %0, %1" : "+v"(x), "+v"(y));
}

// ---------------- K1: fused kf + qb projections ----------------
// grid 512: blocks 0..255 = qb (bg, j-half), blocks 256..511 = kf (b, i-group)
// block 1024 threads; union LDS ~36 KB -> 2 blocks/CU, both roles co-resident.
__global__ __launch_bounds__(1024) void k_pre(const float* __restrict__ q,
    const float* __restrict__ k,
    const float* __restrict__ Wq, const float* __restrict__ bq,
    const float* __restrict__ Wk, const float* __restrict__ bk,
    uint32_t* __restrict__ qb_pack, uint32_t* __restrict__ kf_pack)
{
    __shared__ float buf[9248];
    int t = threadIdx.x;
    int blk = blockIdx.x;
    if (blk < 256){
        // ---------- qb projection ----------
        float* Wq_s = buf;            // 1024
        float* bq_s = buf + 1024;     // 32
        float* q_s  = buf + 1056;     // 8192  (layout [c][j], 32 x 256)
        int bg = blk >> 1, h = blk & 1;
        int b = bg >> 6, g = bg & 63;
        int bh = g >> 4, bw = (g >> 2) & 3, bd = g & 3;
        Wq_s[t] = Wq[t];
        if (t < 32) bq_s[t] = bq[t];
        const float* qbase = q + (size_t)b * 1048576;
        #pragma unroll
        for (int m = 0; m < 2; ++m){
            int L4 = m*1024 + t;
            int f4 = L4 & 1, iw = (L4 >> 1) & 7, ihl = (L4 >> 4) & 3, c = L4 >> 6;
            const float* src = qbase + c*32768 + (bh*8 + h*4 + ihl)*1024
                             + (bw*8 + iw)*32 + bd*8 + f4*4;
            float4 v = *(const float4*)src;
            *(float4*)&q_s[c*256 + ihl*64 + iw*8 + f4*4] = v;
        }
        __syncthreads();
        int d = t & 31, sub = t >> 5;      // sub 0..31
        float wq[32];
        #pragma unroll
        for (int c = 0; c < 32; ++c) wq[c] = Wq_s[c*32 + d];
        uint32_t* qb_out = qb_pack + (size_t)bg * 8192 + h*4096;
        #pragma unroll
        for (int it = 0; it < 2; ++it){
            int jl = it*128 + sub*4;
            float bb = bq_s[d];
            float a0 = bb, a1 = bb, a2 = bb, a3 = bb;
            #pragma unroll
            for (int c = 0; c < 32; ++c){
                float4 qv = *(const float4*)&q_s[c*256 + jl];
                a0 += qv.x * wq[c];
                a1 += qv.y * wq[c];
                a2 += qv.z * wq[c];
                a3 += qv.w * wq[c];
            }
            float b0 = __shfl_xor(a0, 1, 64), b1 = __shfl_xor(a1, 1, 64);
            float b2 = __shfl_xor(a2, 1, 64), b3 = __shfl_xor(a3, 1, 64);
            if ((d & 1) == 0){
                int w0 = d >> 1;
                qb_out[(jl+0)*16 + w0] = pack2(a0, b0);
                qb_out[(jl+1)*16 + w0] = pack2(a1, b1);
                qb_out[(jl+2)*16 + w0] = pack2(a2, b2);
                qb_out[(jl+3)*16 + w0] = pack2(a3, b3);
            }
        }
    } else {
        // ---------- kf projection ----------
        float* Wk_s = buf;            // 8192
        float* bk_s = buf + 8192;     // 32
        float* red  = buf + 8224;     // 1024 (32 x 32)
        for (int L = t; L < 8192; L += 1024) Wk_s[L] = Wk[L];
        if (t < 32) bk_s[t] = bk[t];
        __syncthreads();
        int kb_blk = blk - 256;
        int b = kb_blk >> 7, i0 = (kb_blk & 127) * 4;
        int d = t & 31, sub = t >> 5;
        int i = i0 + (sub >> 3);
        int cp = sub & 7;
        const float* kbp = k + (size_t)b * 131072;
        float acc = 0.f;
        #pragma unroll 8
        for (int cc = 0; cc < 32; ++cc){
            int c = cp*32 + cc;
            acc += kbp[c*512 + i] * Wk_s[c*32 + d];
        }
        red[sub*32 + d] = acc;
        __syncthreads();
        if (t < 128){
            int isel = t >> 5, dd = t & 31;
            float s = bk_s[dd];
            #pragma unroll
            for (int cp2 = 0; cp2 < 8; ++cp2) s += red[(isel*8 + cp2)*32 + dd];
            float sO = __shfl_xor(s, 1, 64);
            if ((dd & 1) == 0)
                kf_pack[(b*512 + i0 + isel)*16 + (dd >> 1)] = pack2(s, sO);
        }
    }
}

// ---------------- K2: MFMA attention, in-register P via permlane ----------------
// grid 512 = (bg, j-quarter); block 512 = 8 waves; ~77 KB LDS -> 2 blocks/CU.
// Swapped QK^T (A=kf,B=qb) so lane holds S^T; exp+cvt_pk+permlane builds the PV
// B-fragment in registers -- no P LDS round trip.
__global__ __launch_bounds__(512) void k_attn_mfma(const uint32_t* __restrict__ kf_pack,
    const uint32_t* __restrict__ qb_pack,
    float* __restrict__ oraw, float* __restrict__ mnp, float* __restrict__ mxp)
{
    __shared__ uint32_t kfs32[8192];     // 32 KB: kf [512 i][16 dp] swizzled
    __shared__ uint16_t qbV16[16384];    // 32 KB: qb^T [32 d][512 i] swizzled
    __shared__ float mred[8][64];        // 2 KB
    __shared__ float stat[32][32];       // 4 KB
    __shared__ float knsh[32], vssh[32], dsh[32];
    __shared__ float denom_s;
    int t = threadIdx.x;
    int blk = blockIdx.x;
    int bg = blk >> 2, jq = blk & 3;
    int b = bg >> 6;
    // ---- stage kf (full 512 i) ----
    {
        const uint32_t* src = kf_pack + b*8192;
        #pragma unroll
        for (int m = 0; m < 16; ++m){
            int flat = m*512 + t;
            uint32_t v = src[flat];
            int i = flat >> 4, dp = flat & 15;
            kfs32[i*16 + (((dp>>2) ^ (i&3)) & 3)*4 + (dp&3)] = v;
        }
    }
    // ---- stage qbV (full 512 i) ----
    {
        const uint32_t* src = qb_pack + (size_t)bg*8192;
        #pragma unroll
        for (int m = 0; m < 16; ++m){
            int flat = m*512 + t;
            int i = flat >> 4, dp = flat & 15;
            uint32_t v = src[flat];
            int d0 = 2*dp, d1 = 2*dp + 1;
            qbV16[d0*512 + (((i>>3) ^ (d0&7)) & 63)*8 + (i&7)] = (uint16_t)(v & 0xffffu);
            qbV16[d1*512 + (((i>>3) ^ (d1&7)) & 63)*8 + (i&7)] = (uint16_t)(v >> 16);
        }
    }
    __syncthreads();
    // ---- prologue 1: knorm2 ----
    {
        int dp = t & 15, ig = t >> 4;            // 32 groups of 16 i
        float lo2 = 0.f, hi2 = 0.f;
        #pragma unroll
        for (int ii = 0; ii < 16; ++ii){
            int i = ig*16 + ii;
            uint32_t u = kfs32[i*16 + (((dp>>2) ^ (i&3)) & 3)*4 + (dp&3)];
            float a = lo16(u), c = hi16(u);
            lo2 += a*a; hi2 += c*c;
        }
        stat[ig][dp*2] = lo2; stat[ig][dp*2+1] = hi2;
    }
    __syncthreads();
    if (t < 32){
        float s = 0.f;
        #pragma unroll
        for (int u = 0; u < 32; ++u) s += stat[u][t];
        knsh[t] = s;
    }
    __syncthreads();
    // ---- prologue 2: qn2 + vsum ----
    {
        int d = t & 31, ig = t >> 5;             // 16 groups of 32 i
        float q2 = 0.f, vs = 0.f;
        #pragma unroll
        for (int ii = 0; ii < 32; ii += 2){
            int i = ig*32 + ii;
            uint32_t u = *(__shared__ uint32_t*)&qbV16[d*512 + (((i>>3) ^ (d&7)) & 63)*8 + (i&7)];
            float a = lo16(u), c = hi16(u);
            q2 += a*a + c*c; vs += a + c;
        }
        stat[ig][d] = q2; stat[16 + ig][d] = vs;
    }
    __syncthreads();
    if (t < 32){
        float q2 = 0.f, vs = 0.f;
        #pragma unroll
        for (int u = 0; u < 16; ++u){ q2 += stat[u][t]; vs += stat[16+u][t]; }
        vssh[t] = vs;
        dsh[t] = sqrtf(knsh[t]) * sqrtf(q2);
    }
    __syncthreads();
    if (t == 0){
        float s = 0.f;
        #pragma unroll
        for (int d2 = 0; d2 < 32; ++d2) s += dsh[d2];
        denom_s = s + 1e-4f;
    }
    __syncthreads();
    float rden = 1.0f / denom_s;
    int wave = t >> 6, lane = t & 63;
    int ln15 = lane & 15, quad = lane >> 4;
    float vs0[4], vs1[4];
    #pragma unroll
    for (int r = 0; r < 4; ++r){
        vs0[r] = vssh[quad*4 + r];
        vs1[r] = vssh[16 + quad*4 + r];
    }
    float* obase = oraw + (size_t)bg * 16384;
    int jloc = jq*128 + wave*16 + ln15;          // j within bg (0..511)
    // afr: qb B-fragment for this wave's 16 j (col=ln15=j, k=d=quad*8+jj)
    union { bf16x8 v; uint16_t u[8]; } afr;
    #pragma unroll
    for (int jj = 0; jj < 8; ++jj){
        int d = quad*8 + jj;
        afr.u[jj] = qbV16[d*512 + (((jloc>>3) ^ (d&7)) & 63)*8 + (jloc&7)];
    }
    f32x4 pv0 = {0.f,0.f,0.f,0.f}, pv1 = {0.f,0.f,0.f,0.f};
    float pdn = 0.f;
    for (int sb = 0; sb < 4; ++sb){
        #pragma unroll
        for (int ch = 0; ch < 4; ++ch){
            int ib = sb*128 + ch*32;
            int i0 = ib + ln15;
            int i1 = i0 + 16;
            bf16x8 k0 = *(__shared__ bf16x8*)&kfs32[i0*16 + ((quad ^ (i0&3)) & 3)*4];
            bf16x8 k1 = *(__shared__ bf16x8*)&kfs32[i1*16 + ((quad ^ (i1&3)) & 3)*4];
            f32x4 z = {0.f,0.f,0.f,0.f};
            // swapped QK: S^T tile; lane: j=ln15 (col), i=quad*4+r (row)
            f32x4 s0 = __builtin_amdgcn_mfma_f32_16x16x32_bf16(k0, afr.v, z, 0, 0, 0);
            f32x4 s1 = __builtin_amdgcn_mfma_f32_16x16x32_bf16(k1, afr.v, z, 0, 0, 0);
            float e0[4], e1[4];
            #pragma unroll
            for (int r = 0; r < 4; ++r){
                float x = s0[r] * rden;
                e0[r] = x + x*x*(0.5f + x*(1.0f/6.0f));
                pdn += e0[r];
                x = s1[r] * rden;
                e1[r] = x + x*x*(0.5f + x*(1.0f/6.0f));
                pdn += e1[r];
            }
            uint32_t A0 = cvtpk(e0[0], e0[1]);
            uint32_t A1 = cvtpk(e0[2], e0[3]);
            uint32_t B0 = cvtpk(e1[0], e1[1]);
            uint32_t B1 = cvtpk(e1[2], e1[3]);
            // in-register transpose to PV B-fragment (k=i=quad*8+jj, col=j=ln15)
            pl32swap(A0, B0); pl16swap(A0, B0);   // A0 = w0, B0 = w2
            pl32swap(A1, B1); pl16swap(A1, B1);   // A1 = w1, B1 = w3
            union { bf16x8 v; uint32_t w[4]; } bp;
            bp.w[0] = A0; bp.w[1] = A1; bp.w[2] = B0; bp.w[3] = B1;
            int ig = ib + quad*8;
            int c0 = ln15, c1 = 16 + ln15;
            bf16x8 av0 = *(__shared__ bf16x8*)&qbV16[c0*512 + (((ig>>3) ^ (c0&7)) & 63)*8];
            bf16x8 av1 = *(__shared__ bf16x8*)&qbV16[c1*512 + (((ig>>3) ^ (c1&7)) & 63)*8];
            pv0 = __builtin_amdgcn_mfma_f32_16x16x32_bf16(av0, bp.v, pv0, 0, 0, 0);
            pv1 = __builtin_amdgcn_mfma_f32_16x16x32_bf16(av1, bp.v, pv1, 0, 0, 0);
        }
    }
    // ---- epilogue: denom (quad reduce), o write, min/max ----
    pdn += __shfl_xor(pdn, 16, 64);
    pdn += __shfl_xor(pdn, 32, 64);
    float rl = 1.0f / (512.f + pdn);
    float o0[4], o1[4];
    #pragma unroll
    for (int r = 0; r < 4; ++r){
        o0[r] = (vs0[r] + pv0[r]) * rl;
        o1[r] = (vs1[r] + pv1[r]) * rl;
        obase[(quad*4 + r)*512 + jloc]      = o0[r];
        obase[(16 + quad*4 + r)*512 + jloc] = o1[r];
    }
    #pragma unroll
    for (int r = 0; r < 4; ++r){
        float mnA = o0[r], mxA = o0[r], mnB = o1[r], mxB = o1[r];
        #pragma unroll
        for (int off = 1; off < 16; off <<= 1){
            mnA = fminf(mnA, __shfl_xor(mnA, off, 64));
            mxA = fmaxf(mxA, __shfl_xor(mxA, off, 64));
            mnB = fminf(mnB, __shfl_xor(mnB, off, 64));
            mxB = fmaxf(mxB, __shfl_xor(mxB, off, 64));
        }
        if (ln15 == 0){
            mred[wave][quad*4 + r]      = mnA;
            mred[wave][32 + quad*4 + r] = mxA;
            mred[wave][16 + quad*4 + r] = mnB;
            mred[wave][48 + quad*4 + r] = mxB;
        }
    }
    __syncthreads();
    if (t < 32){
        float mn = 3e38f, mx = -3e38f;
        #pragma unroll
        for (int w = 0; w < 8; ++w){
            mn = fminf(mn, mred[w][t]);
            mx = fmaxf(mx, mred[w][32 + t]);
        }
        int slot = (bg*4 + jq)*32 + t;
        mnp[slot] = mn;
        mxp[slot] = mx;
    }
}

// ---------------- K3: scrambled gather + fused renorm + Wp projection ----------------
// grid 2048; block 256; 32 positions/block, 4 gathers+outputs per thread
__global__ __launch_bounds__(256) void k_proj(const float* __restrict__ oraw,
    const float* __restrict__ mnp, const float* __restrict__ mxp,
    const float* __restrict__ Wp, const float* __restrict__ bp,
    float* __restrict__ out)
{
    __shared__ float Wp_s[1024], bp_s[32];
    __shared__ float sh_v[32][32];
    __shared__ float sh_o[32][33];
    int t = threadIdx.x;
    if (t < 32) bp_s[t] = bp[t];
    for (int L = t; L < 1024; L += 256) Wp_s[L] = Wp[L];
    int blk = blockIdx.x;
    int b = blk >> 10, p0 = (blk & 1023) * 32;
    int c = t & 31, ip0 = t >> 5;
    float vv[4];
    #pragma unroll
    for (int m = 0; m < 4; ++m){
        int p = p0 + m*8 + ip0;
        int h = p >> 10, w = (p >> 5) & 31, dsp = p & 31;
        int f = (h >> 3)*262144 + (w >> 3)*65536 + (dsp >> 3)*16384
              + (h & 7)*2048 + (w & 7)*256 + (dsp & 7)*32;
        int flat = f + c;
        int cidx = b*2048 + (flat >> 9);         // bg*32 + channel
        int s0 = ((cidx >> 5) << 7) + (cidx & 31);
        float o  = oraw[(size_t)b*1048576 + flat];
        float mn = fminf(fminf(mnp[s0], mnp[s0 + 32]), fminf(mnp[s0 + 64], mnp[s0 + 96]));
        float mx = fmaxf(fmaxf(mxp[s0], mxp[s0 + 32]), fmaxf(mxp[s0 + 64], mxp[s0 + 96]));
        vv[m] = (o - mn) / (mx - mn + 1e-4f);
    }
    __syncthreads();
    #pragma unroll
    for (int m = 0; m < 4; ++m) sh_v[m*8 + ip0][c] = vv[m];
    __syncthreads();
    #pragma unroll
    for (int m = 0; m < 4; ++m){
        int pos = m*8 + ip0;
        float acc = bp_s[c];
        #pragma unroll
        for (int cc = 0; cc < 32; ++cc)
            acc += sh_v[pos][cc] * Wp_s[cc*32 + c];
        sh_o[pos][c] = acc;
    }
    __syncthreads();
    #pragma unroll
    for (int m = 0; m < 4; ++m){
        int e = m*8 + (t >> 5), pi = t & 31;
        out[((size_t)(b*32 + e) << 15) + p0 + pi] = sh_o[pi][e];
    }
}

extern "C" void kernel_launch(void* const* d_in, const int* in_sizes, int n_in,
                              void* d_out, int out_size, void* d_ws, size_t ws_size,
                              hipStream_t stream)
{
    const float* q  = (const float*)d_in[0];
    const float* k  = (const float*)d_in[1];
    const float* Wq = (const float*)d_in[2];
    const float* bq = (const float*)d_in[3];
    const float* Wk = (const float*)d_in[4];
    const float* bk = (const float*)d_in[5];
    const float* Wp = (const float*)d_in[6];
    const float* bp = (const float*)d_in[7];

    float* base      = (float*)d_ws;
    uint32_t* kf_pack = (uint32_t*)base;                // 16384 u32
    uint32_t* qb_pack = (uint32_t*)(base + 16384);      // 1,048,576 u32
    float* oraw      = base + 1064960;                  // 2,097,152 f
    float* mnp       = base + 3162112;                  // 16384 f
    float* mxp       = base + 3178496;                  // 16384 f (~12.8 MB total)
    float* outp      = (float*)d_out;

    hipLaunchKernelGGL(k_pre,       dim3(512),  dim3(1024), 0, stream, q, k, Wq, bq, Wk, bk, qb_pack, kf_pack);
    hipLaunchKernelGGL(k_attn_mfma, dim3(512),  dim3(512),  0, stream, kf_pack, qb_pack, oraw, mnp, mxp);
    hipLaunchKernelGGL(k_proj,      dim3(2048), dim3(256),  0, stream, oraw, mnp, mxp, Wp, bp, outp);
}